// Round 6
// baseline (291.390 us; speedup 1.0000x reference)
//
#include <hip/hip_runtime.h>
#include <stdint.h>

typedef int v4i  __attribute__((ext_vector_type(4)));
typedef int v16i __attribute__((ext_vector_type(16)));

#define DIN 1024
#define QMAXF 127.0f

__device__ __forceinline__ float amax4(float4 u) {
    return fmaxf(fmaxf(fabsf(u.x), fabsf(u.y)), fmaxf(fabsf(u.z), fabsf(u.w)));
}

__device__ __forceinline__ float wave_max64(float a) {
    #pragma unroll
    for (int off = 32; off; off >>= 1)
        a = fmaxf(a, __shfl_xor(a, off));
    return a;
}

__device__ __forceinline__ unsigned pack4(float4 u, float inv) {
    int q0 = max(-128, min(127, __float2int_rn(u.x * inv)));
    int q1 = max(-128, min(127, __float2int_rn(u.y * inv)));
    int q2 = max(-128, min(127, __float2int_rn(u.z * inv)));
    int q3 = max(-128, min(127, __float2int_rn(u.w * inv)));
    return (unsigned)(q0 & 255) | ((unsigned)(q1 & 255) << 8) |
           ((unsigned)(q2 & 255) << 16) | ((unsigned)(q3 & 255) << 24);
}

// Weight quant + swizzle into MFMA-fragment-coalesced layout.
// 16B chunk (n, k16) -> slot [((n>>5)*32 + (k16>>1))*64 + (n&31) + 32*(k16&1)]
// so a wave's K-loop fragment load is ONE contiguous 1KB segment.
__global__ __launch_bounds__(256) void quant_w(
    const float* __restrict__ w, char* __restrict__ wq,
    float* __restrict__ wscale)
{
    int wave = threadIdx.x >> 6;
    int lane = threadIdx.x & 63;
    int r = blockIdx.x * 4 + wave;

    const float* src = w + (size_t)r * DIN;

    float4 v[4];
    #pragma unroll
    for (int j = 0; j < 4; j++)
        v[j] = ((const float4*)src)[lane * 4 + j];

    float a = 0.0f;
    #pragma unroll
    for (int j = 0; j < 4; j++)
        a = fmaxf(a, amax4(v[j]));
    a = fmaxf(wave_max64(a), 1e-8f);

    float inv = QMAXF / a;
    int pk[4];
    #pragma unroll
    for (int j = 0; j < 4; j++)
        pk[j] = (int)pack4(v[j], inv);
    v4i pkv = { pk[0], pk[1], pk[2], pk[3] };

    int nb  = r >> 5;
    int ks  = lane >> 1;
    int sub = (r & 31) + 32 * (lane & 1);
    ((v4i*)wq)[(size_t)(nb * 32 + ks) * 64 + sub] = pkv;

    if (lane == 0) wscale[r] = a / QMAXF;
}

// Per-token activation quant -> int8 A in MFMA-fragment order.
// Global aq layout (16B units): 32-row slab g (= m/32), k16 chunk c, row r:
//   slot = g*2048 + c*32 + r
// so a GEMM wave's A-fragment load at K-step ks is slab + ks*1024 + lane*16
// = ONE contiguous 1KB segment. Transpose via LDS:
//   write slot' = (s & ~31) | ((r ^ c) & 31)   (banks: 2 lanes/bank = free)
//   readout linear u -> lds (u & ~31) | ((u ^ (u>>5)) & 31)  (permutation of
//   32 consecutive 16B slots per 32 lanes = conflict-free)
// Coalesced fp32 reads, coalesced 16B writes. Pure streaming.
__global__ __launch_bounds__(512) void quant_x(
    const float* __restrict__ x, char* __restrict__ aq,
    float* __restrict__ xscale)
{
    __shared__ char Ls[65536];

    int m0 = blockIdx.x * 64;
    int w = threadIdx.x >> 6;
    int lane = threadIdx.x & 63;

    for (int i = 0; i < 8; i++) {
        int r = w * 8 + i;
        const float* src = x + (size_t)(m0 + r) * DIN;
        float4 v[4];
        #pragma unroll
        for (int j = 0; j < 4; j++)
            v[j] = ((const float4*)src)[lane + 64 * j];   // lane-stride 16B

        float a = fmaxf(fmaxf(amax4(v[0]), amax4(v[1])),
                        fmaxf(amax4(v[2]), amax4(v[3])));
        a = fmaxf(wave_max64(a), 1e-8f);
        float inv = QMAXF / a;

        #pragma unroll
        for (int j = 0; j < 4; j++) {
            unsigned pk = pack4(v[j], inv);
            int D = lane + 64 * j;              // dword index in row
            int c = D >> 2;                     // 16B k-chunk (0..63)
            int s = ((r >> 5) << 11) + (c << 5) + (r & 31);
            int sp = (s & ~31) | ((s ^ (s >> 5)) & 31);   // == r^c in low 5
            *(unsigned*)(Ls + sp * 16 + (D & 3) * 4) = pk;
        }
        if (lane == 0) xscale[m0 + r] = a / QMAXF;
    }
    __syncthreads();

    v4i* g = (v4i*)(aq + (size_t)blockIdx.x * 65536);
    #pragma unroll
    for (int j = 0; j < 8; j++) {
        int u = threadIdx.x + (j << 9);
        int up = (u & ~31) | ((u ^ (u >> 5)) & 31);
        g[u] = *(const v4i*)(Ls + up * 16);
    }
}

// int8 GEMM, ZERO LDS / ZERO barriers: all operands stream from global
// (A: fragment-order aq, L2/L3-hot just-written; B: fragment-order wq, 1MB
// L2-resident). Block = 256 threads (4 waves), tile 32M x 512N; per wave
// 32M x 128N = 4 N-frags of 32x32 (64 AGPR). launch_bounds(256,4): <=128
// unified regs -> 4 waves/SIMD; grid 2048 = 8 blocks/CU -> 32 free-running
// waves/CU with 1-iter register prefetch. Latency hiding by TLP, not
// barriers -- no phase serialization anywhere.
__global__ __launch_bounds__(256, 4) void gemm_i8(
    const char* __restrict__ Aq, const char* __restrict__ Bq,
    const float* __restrict__ xscale, const float* __restrict__ wscale,
    const float* __restrict__ bias, float* __restrict__ out, int N)
{
    int mtile = blockIdx.x >> 1;       // 32-row slab index (0..1023)
    int nhalf = blockIdx.x & 1;
    int w = threadIdx.x >> 6;          // 0..3
    int lane = threadIdx.x & 63;
    int sel = lane >> 5;

    const char* ap = Aq + (size_t)mtile * 32768 + (size_t)lane * 16;
    int cw = nhalf * 4 + w;            // N-group 0..7 (128 cols each)
    const char* bp = Bq + (size_t)cw * 131072 + (size_t)lane * 16;

    v16i acc0 = {}, acc1 = {}, acc2 = {}, acc3 = {};

    v4i aC  = *(const v4i*)(ap);
    v4i bC0 = *(const v4i*)(bp);
    v4i bC1 = *(const v4i*)(bp + 32768);
    v4i bC2 = *(const v4i*)(bp + 65536);
    v4i bC3 = *(const v4i*)(bp + 98304);

    #pragma unroll 4
    for (int ks = 0; ks < 32; ks++) {
        v4i aN, bN0, bN1, bN2, bN3;
        if (ks < 31) {
            aN  = *(const v4i*)(ap + (ks + 1) * 1024);
            const char* bn = bp + (ks + 1) * 1024;
            bN0 = *(const v4i*)(bn);
            bN1 = *(const v4i*)(bn + 32768);
            bN2 = *(const v4i*)(bn + 65536);
            bN3 = *(const v4i*)(bn + 98304);
        }
        acc0 = __builtin_amdgcn_mfma_i32_32x32x32_i8(aC, bC0, acc0, 0, 0, 0);
        acc1 = __builtin_amdgcn_mfma_i32_32x32x32_i8(aC, bC1, acc1, 0, 0, 0);
        acc2 = __builtin_amdgcn_mfma_i32_32x32x32_i8(aC, bC2, acc2, 0, 0, 0);
        acc3 = __builtin_amdgcn_mfma_i32_32x32x32_i8(aC, bC3, acc3, 0, 0, 0);
        aC = aN; bC0 = bN0; bC1 = bN1; bC2 = bN2; bC3 = bN3;
    }

    // epilogue: C/D layout col=lane&31, row=(reg&3)+8*(reg>>2)+4*sel
    int n_lane = lane & 31;
    int mrow0 = mtile * 32;
    v16i accs[4] = {acc0, acc1, acc2, acc3};
    #pragma unroll
    for (int j = 0; j < 4; j++) {
        int n = cw * 128 + j * 32 + n_lane;
        float wsn = wscale[n];
        float bn = bias[n];
        #pragma unroll
        for (int r = 0; r < 16; r++) {
            int ml = (r & 3) + 8 * (r >> 2) + 4 * sel;
            __builtin_nontemporal_store(
                (float)accs[j][r] * xscale[mrow0 + ml] * wsn + bn,
                &out[(size_t)(mrow0 + ml) * N + n]);
        }
    }
}

extern "C" void kernel_launch(void* const* d_in, const int* in_sizes, int n_in,
                              void* d_out, int out_size, void* d_ws, size_t ws_size,
                              hipStream_t stream)
{
    const float* x    = (const float*)d_in[0];
    const float* w    = (const float*)d_in[1];
    const float* bias = (const float*)d_in[2];
    float* out = (float*)d_out;

    int DOUT = in_sizes[2];        // 1024
    int M = in_sizes[0] / DIN;     // 32768

    char* ws   = (char*)d_ws;
    char* wq   = ws;                                    // DOUT*DIN int8
    float* wsc = (float*)(wq + (size_t)DOUT * DIN);     // DOUT f32
    float* xsc = wsc + DOUT;                            // M f32
    char* aq   = (char*)(xsc + M);                      // M*DIN int8 (frag order)

    quant_w<<<DOUT / 4, 256, 0, stream>>>(w, wq, wsc);
    quant_x<<<M / 64, 512, 0, stream>>>(x, aq, xsc);
    gemm_i8<<<M / 16 /* (M/32)*2 */, 256, 0, stream>>>(aq, wq, xsc, wsc, bias, out, DOUT);
}

// Round 7
// 279.387 us; speedup vs baseline: 1.0430x; 1.0430x over previous
//
#include <hip/hip_runtime.h>
#include <stdint.h>

typedef int v4i  __attribute__((ext_vector_type(4)));
typedef int v16i __attribute__((ext_vector_type(16)));

#define DIN 1024
#define QMAXF 127.0f

__device__ __forceinline__ float amax4(float4 u) {
    return fmaxf(fmaxf(fabsf(u.x), fabsf(u.y)), fmaxf(fabsf(u.z), fabsf(u.w)));
}

__device__ __forceinline__ float wave_max64(float a) {
    #pragma unroll
    for (int off = 32; off; off >>= 1)
        a = fmaxf(a, __shfl_xor(a, off));
    return a;
}

__device__ __forceinline__ unsigned pack4(float4 u, float inv) {
    int q0 = max(-128, min(127, __float2int_rn(u.x * inv)));
    int q1 = max(-128, min(127, __float2int_rn(u.y * inv)));
    int q2 = max(-128, min(127, __float2int_rn(u.z * inv)));
    int q3 = max(-128, min(127, __float2int_rn(u.w * inv)));
    return (unsigned)(q0 & 255) | ((unsigned)(q1 & 255) << 8) |
           ((unsigned)(q2 & 255) << 16) | ((unsigned)(q3 & 255) << 24);
}

// Weight quant + swizzle into MFMA-fragment-coalesced layout.
// 16B chunk (n, k16) -> slot [((n>>5)*32 + (k16>>1))*64 + (n&31) + 32*(k16&1)]
// so a wave's B-fragment load is ONE contiguous segment (lane i at +16*i).
__global__ __launch_bounds__(256) void quant_w(
    const float* __restrict__ w, char* __restrict__ wq,
    float* __restrict__ wscale)
{
    int wave = threadIdx.x >> 6;
    int lane = threadIdx.x & 63;
    int r = blockIdx.x * 4 + wave;

    const float* src = w + (size_t)r * DIN;

    float4 v[4];
    #pragma unroll
    for (int j = 0; j < 4; j++)
        v[j] = ((const float4*)src)[lane * 4 + j];

    float a = 0.0f;
    #pragma unroll
    for (int j = 0; j < 4; j++)
        a = fmaxf(a, amax4(v[j]));
    a = fmaxf(wave_max64(a), 1e-8f);

    float inv = QMAXF / a;
    int pk[4];
    #pragma unroll
    for (int j = 0; j < 4; j++)
        pk[j] = (int)pack4(v[j], inv);
    v4i pkv = { pk[0], pk[1], pk[2], pk[3] };

    int nb  = r >> 5;
    int ks  = lane >> 1;
    int sub = (r & 31) + 32 * (lane & 1);
    ((v4i*)wq)[(size_t)(nb * 32 + ks) * 64 + sub] = pkv;

    if (lane == 0) wscale[r] = a / QMAXF;
}

// Per-token activation quant -> int8 A in MFMA-fragment order (verified r6).
// Global aq layout (16B units): 32-row slab g (= m/32), k16 chunk c, row r:
//   slot = g*2048 + c*32 + r  (clean order; XOR swizzle is LDS-internal only)
__global__ __launch_bounds__(512) void quant_x(
    const float* __restrict__ x, char* __restrict__ aq,
    float* __restrict__ xscale)
{
    __shared__ char Ls[65536];

    int m0 = blockIdx.x * 64;
    int w = threadIdx.x >> 6;
    int lane = threadIdx.x & 63;

    for (int i = 0; i < 8; i++) {
        int r = w * 8 + i;
        const float* src = x + (size_t)(m0 + r) * DIN;
        float4 v[4];
        #pragma unroll
        for (int j = 0; j < 4; j++)
            v[j] = ((const float4*)src)[lane + 64 * j];   // lane-stride 16B

        float a = fmaxf(fmaxf(amax4(v[0]), amax4(v[1])),
                        fmaxf(amax4(v[2]), amax4(v[3])));
        a = fmaxf(wave_max64(a), 1e-8f);
        float inv = QMAXF / a;

        #pragma unroll
        for (int j = 0; j < 4; j++) {
            unsigned pk = pack4(v[j], inv);
            int D = lane + 64 * j;              // dword index in row
            int c = D >> 2;                     // 16B k-chunk (0..63)
            int s = ((r >> 5) << 11) + (c << 5) + (r & 31);
            int sp = (s & ~31) | ((s ^ (s >> 5)) & 31);   // == r^c in low 5
            *(unsigned*)(Ls + sp * 16 + (D & 3) * 4) = pk;
        }
        if (lane == 0) xscale[m0 + r] = a / QMAXF;
    }
    __syncthreads();

    v4i* g = (v4i*)(aq + (size_t)blockIdx.x * 65536);
    #pragma unroll
    for (int j = 0; j < 8; j++) {
        int u = threadIdx.x + (j << 9);
        int up = (u & ~31) | ((u ^ (u >> 5)) & 31);
        g[u] = *(const v4i*)(Ls + up * 16);
    }
}

// int8 GEMM with square per-wave tiles (the L2-rate fix).
// Block = 512 thr / 8 waves, tile 64M x 512N; per wave 64M x 64N:
//   2 A-frags (LDS) + 2 B-frags (L2) per 4 MFMA -> B demand ~56 GB/s/CU,
//   well under the 135 GB/s/CU L2 share (previous rounds: 140-165 = saturated).
// A staged once per block: 64KB via global_load_lds (linear, zero VGPR,
// conflict-free ds_read_b128 fragments), ONE barrier total.
// LDS 64KB + ~106 regs -> 2 blocks/CU co-resident: one block's stage/epilogue
// overlaps the other's K-loop. Grid = (M/64)*2 = 1024.
__global__ __launch_bounds__(512, 4) void gemm_i8(
    const char* __restrict__ Aq, const char* __restrict__ Bq,
    const float* __restrict__ xscale, const float* __restrict__ wscale,
    const float* __restrict__ bias, float* __restrict__ out, int N)
{
    __shared__ char As[65536];

    int mtile = blockIdx.x >> 1;       // 64-row tile (0..511)
    int nblk  = blockIdx.x & 1;        // 512-col half
    int w = threadIdx.x >> 6;          // 0..7
    int lane = threadIdx.x & 63;
    int sel = lane >> 5;

    // ---- stage A tile (64KB, fragment order) into LDS ----
    {
        const char* slab = Aq + (size_t)mtile * 65536;
        #pragma unroll
        for (int j = 0; j < 8; j++) {
            int idx = threadIdx.x + (j << 9);
            __builtin_amdgcn_global_load_lds(
                (const __attribute__((address_space(1))) unsigned*)(slab + idx * 16),
                (__attribute__((address_space(3))) unsigned*)(&As[idx * 16]),
                16, 0, 0);
        }
    }
    __syncthreads();   // drains vmcnt(0): A resident

    // ---- K loop: per wave 64M x 64N ----
    int n0 = nblk * 512 + w * 64;
    const char* bp = Bq + (size_t)(n0 >> 5) * 32768 + (size_t)lane * 16;
    const char* ap = As + lane * 16;

    v16i acc00 = {}, acc01 = {}, acc10 = {}, acc11 = {};

    v4i aC0 = *(const v4i*)(ap);
    v4i aC1 = *(const v4i*)(ap + 32768);
    v4i bC0 = *(const v4i*)(bp);
    v4i bC1 = *(const v4i*)(bp + 32768);

    #pragma unroll 4
    for (int ks = 0; ks < 32; ks++) {
        v4i aN0, aN1, bN0, bN1;
        if (ks < 31) {
            aN0 = *(const v4i*)(ap + (ks + 1) * 1024);
            aN1 = *(const v4i*)(ap + (ks + 1) * 1024 + 32768);
            bN0 = *(const v4i*)(bp + (ks + 1) * 1024);
            bN1 = *(const v4i*)(bp + (ks + 1) * 1024 + 32768);
        }
        acc00 = __builtin_amdgcn_mfma_i32_32x32x32_i8(aC0, bC0, acc00, 0, 0, 0);
        acc01 = __builtin_amdgcn_mfma_i32_32x32x32_i8(aC0, bC1, acc01, 0, 0, 0);
        acc10 = __builtin_amdgcn_mfma_i32_32x32x32_i8(aC1, bC0, acc10, 0, 0, 0);
        acc11 = __builtin_amdgcn_mfma_i32_32x32x32_i8(aC1, bC1, acc11, 0, 0, 0);
        aC0 = aN0; aC1 = aN1; bC0 = bN0; bC1 = bN1;
    }

    // ---- epilogue: C/D layout col=lane&31, row=(reg&3)+8*(reg>>2)+4*sel ----
    int n_lane = lane & 31;
    int m0 = mtile * 64;
    v16i accs[2][2] = {{acc00, acc01}, {acc10, acc11}};
    #pragma unroll
    for (int mi = 0; mi < 2; mi++) {
        #pragma unroll
        for (int nj = 0; nj < 2; nj++) {
            int n = n0 + nj * 32 + n_lane;
            float wsn = wscale[n];
            float bn = bias[n];
            v16i A = accs[mi][nj];
            #pragma unroll
            for (int r = 0; r < 16; r++) {
                int ml = mi * 32 + (r & 3) + 8 * (r >> 2) + 4 * sel;
                __builtin_nontemporal_store(
                    (float)A[r] * xscale[m0 + ml] * wsn + bn,
                    &out[(size_t)(m0 + ml) * N + n]);
            }
        }
    }
}

extern "C" void kernel_launch(void* const* d_in, const int* in_sizes, int n_in,
                              void* d_out, int out_size, void* d_ws, size_t ws_size,
                              hipStream_t stream)
{
    const float* x    = (const float*)d_in[0];
    const float* w    = (const float*)d_in[1];
    const float* bias = (const float*)d_in[2];
    float* out = (float*)d_out;

    int DOUT = in_sizes[2];        // 1024
    int M = in_sizes[0] / DIN;     // 32768

    char* ws   = (char*)d_ws;
    char* wq   = ws;                                    // DOUT*DIN int8
    float* wsc = (float*)(wq + (size_t)DOUT * DIN);     // DOUT f32
    float* xsc = wsc + DOUT;                            // M f32
    char* aq   = (char*)(xsc + M);                      // M*DIN int8 (frag order)

    quant_w<<<DOUT / 4, 256, 0, stream>>>(w, wq, wsc);
    quant_x<<<M / 64, 512, 0, stream>>>(x, aq, xsc);
    gemm_i8<<<(M / 64) * 2, 512, 0, stream>>>(aq, wq, xsc, wsc, bias, out, DOUT);
}

// Round 8
// 258.694 us; speedup vs baseline: 1.1264x; 1.0800x over previous
//
#include <hip/hip_runtime.h>
#include <stdint.h>

typedef int v4i  __attribute__((ext_vector_type(4)));
typedef int v16i __attribute__((ext_vector_type(16)));

#define DIN 1024
#define QMAXF 127.0f

__device__ __forceinline__ float amax4(float4 u) {
    return fmaxf(fmaxf(fabsf(u.x), fabsf(u.y)), fmaxf(fabsf(u.z), fabsf(u.w)));
}

__device__ __forceinline__ float wave_max64(float a) {
    #pragma unroll
    for (int off = 32; off; off >>= 1)
        a = fmaxf(a, __shfl_xor(a, off));
    return a;
}

__device__ __forceinline__ unsigned pack4(float4 u, float inv) {
    int q0 = max(-128, min(127, __float2int_rn(u.x * inv)));
    int q1 = max(-128, min(127, __float2int_rn(u.y * inv)));
    int q2 = max(-128, min(127, __float2int_rn(u.z * inv)));
    int q3 = max(-128, min(127, __float2int_rn(u.w * inv)));
    return (unsigned)(q0 & 255) | ((unsigned)(q1 & 255) << 8) |
           ((unsigned)(q2 & 255) << 16) | ((unsigned)(q3 & 255) << 24);
}

// Weight quant + swizzle into MFMA-fragment-coalesced layout.
// 16B chunk (n, k16) -> slot [((n>>5)*32 + (k16>>1))*64 + (n&31) + 32*(k16&1)]
// so a wave's B-fragment load is ONE contiguous 1KB segment (lane i at +16*i).
__global__ __launch_bounds__(256) void quant_w(
    const float* __restrict__ w, char* __restrict__ wq,
    float* __restrict__ wscale)
{
    int wave = threadIdx.x >> 6;
    int lane = threadIdx.x & 63;
    int r = blockIdx.x * 4 + wave;

    const float* src = w + (size_t)r * DIN;

    float4 v[4];
    #pragma unroll
    for (int j = 0; j < 4; j++)
        v[j] = ((const float4*)src)[lane * 4 + j];

    float a = 0.0f;
    #pragma unroll
    for (int j = 0; j < 4; j++)
        a = fmaxf(a, amax4(v[j]));
    a = fmaxf(wave_max64(a), 1e-8f);

    float inv = QMAXF / a;
    int pk[4];
    #pragma unroll
    for (int j = 0; j < 4; j++)
        pk[j] = (int)pack4(v[j], inv);
    v4i pkv = { pk[0], pk[1], pk[2], pk[3] };

    int nb  = r >> 5;
    int ks  = lane >> 1;
    int sub = (r & 31) + 32 * (lane & 1);
    ((v4i*)wq)[(size_t)(nb * 32 + ks) * 64 + sub] = pkv;

    if (lane == 0) wscale[r] = a / QMAXF;
}

// Fused per-token quant + int8 GEMM with square per-wave tiles.
// Block = 512 thr / 8 waves; tile 64M x 512N; per wave 64M x 64N:
//   2 A-frags (LDS) + 2 B-frags (L2) per 4 MFMA -> B demand ~66 GB/s/CU at
//   16 waves/CU (R7-validated, under the ~135 GB/s/CU L2 share; R1/R3's
//   mA=1 tiles demanded ~133 = saturated L2 = the 2x K-phase stall).
// Depth-2 register prefetch on B (3 stages live) rides L2 latency jitter;
// depth-1 on A (LDS latency short).
// ~116 regs + 66KB LDS, __launch_bounds__(512,4) -> 2 blocks/CU: one
// block's quant (HBM read) / epilogue (HBM write) overlaps the other's
// K-loop. Grid = (M/64)*2 = 1024 (mtile = bid>>1, N-half = bid&1).
// A LDS layout (R4-verified conflict-free): chunk (r, c=k16) at slot
// [c*64 + (r^c)]: quant ds_write_b32 = 2 lanes/bank (free); K-phase
// ds_read_b128 = permutation of 64 consecutive 16B slots (conflict-free;
// R4 measured SQ_LDS_BANK_CONFLICT = 0 with this exact pattern).
__global__ __launch_bounds__(512, 4) void gemm_i8_fused(
    const float* __restrict__ x, const char* __restrict__ Bq,
    const float* __restrict__ wscale, const float* __restrict__ bias,
    float* __restrict__ out, int N)
{
    __shared__ char As[64 * 1024];
    __shared__ float xs[64];

    int mtile = blockIdx.x >> 1;
    int nhalf = blockIdx.x & 1;
    int m0 = mtile * 64;
    int w = threadIdx.x >> 6;      // 0..7
    int lane = threadIdx.x & 63;

    // ---- fused quant phase: 8 rows per wave, 1-row load lookahead ----
    {
        const float* src0 = x + (size_t)(m0 + w * 8) * DIN;
        float4 cur[4], nxt[4];
        #pragma unroll
        for (int j = 0; j < 4; j++) cur[j] = ((const float4*)src0)[lane + 64 * j];

        for (int i = 0; i < 8; i++) {
            int r = w * 8 + i;
            if (i < 7) {
                const float* srcn = x + (size_t)(m0 + r + 1) * DIN;
                #pragma unroll
                for (int j = 0; j < 4; j++)
                    nxt[j] = ((const float4*)srcn)[lane + 64 * j];
            }
            float a = fmaxf(fmaxf(amax4(cur[0]), amax4(cur[1])),
                            fmaxf(amax4(cur[2]), amax4(cur[3])));
            a = fmaxf(wave_max64(a), 1e-8f);
            float inv = QMAXF / a;
            #pragma unroll
            for (int j = 0; j < 4; j++) {
                unsigned pk = pack4(cur[j], inv);
                int D = lane + 64 * j;          // dword index in row
                int c = D >> 2;                 // 16B k-chunk (0..63)
                *(unsigned*)(&As[(c * 64 + (r ^ c)) * 16 + (D & 3) * 4]) = pk;
            }
            if (lane == 0) xs[r] = a / QMAXF;
            #pragma unroll
            for (int j = 0; j < 4; j++) cur[j] = nxt[j];
        }
    }
    __syncthreads();

    // ---- K loop: per wave 64M x 64N, B depth-2 prefetch ----
    int frow = lane & 31;
    int sel  = lane >> 5;
    int n0 = nhalf * 512 + w * 64;
    const char* bp = Bq + (size_t)(n0 >> 5) * 32768 + (size_t)lane * 16;

    v16i acc00 = {}, acc01 = {}, acc10 = {}, acc11 = {};

    // A frag addr for k-chunk c, m-half mi: slot c*64 + ((frow+32*mi)^c)
    int c0 = sel;
    v4i aC0 = *(const v4i*)(&As[(c0 * 64 + (frow        ^ c0)) * 16]);
    v4i aC1 = *(const v4i*)(&As[(c0 * 64 + ((frow + 32) ^ c0)) * 16]);

    v4i b0a = *(const v4i*)(bp);
    v4i b1a = *(const v4i*)(bp + 32768);
    v4i b0b = *(const v4i*)(bp + 1024);
    v4i b1b = *(const v4i*)(bp + 1024 + 32768);

    #pragma unroll 4
    for (int ks = 0; ks < 32; ks++) {
        v4i b0n, b1n, aN0, aN1;
        if (ks < 30) {
            const char* bn = bp + (ks + 2) * 1024;
            b0n = *(const v4i*)(bn);
            b1n = *(const v4i*)(bn + 32768);
        }
        if (ks < 31) {
            int cN = 2 * (ks + 1) + sel;
            aN0 = *(const v4i*)(&As[(cN * 64 + (frow        ^ cN)) * 16]);
            aN1 = *(const v4i*)(&As[(cN * 64 + ((frow + 32) ^ cN)) * 16]);
        }
        acc00 = __builtin_amdgcn_mfma_i32_32x32x32_i8(aC0, b0a, acc00, 0, 0, 0);
        acc01 = __builtin_amdgcn_mfma_i32_32x32x32_i8(aC0, b1a, acc01, 0, 0, 0);
        acc10 = __builtin_amdgcn_mfma_i32_32x32x32_i8(aC1, b0a, acc10, 0, 0, 0);
        acc11 = __builtin_amdgcn_mfma_i32_32x32x32_i8(aC1, b1a, acc11, 0, 0, 0);
        b0a = b0b; b1a = b1b; b0b = b0n; b1b = b1n;
        aC0 = aN0; aC1 = aN1;
    }

    // ---- epilogue: C/D layout col=lane&31, row=(reg&3)+8*(reg>>2)+4*sel ----
    int n_lane = lane & 31;
    v16i accs[2][2] = {{acc00, acc01}, {acc10, acc11}};
    #pragma unroll
    for (int mi = 0; mi < 2; mi++) {
        #pragma unroll
        for (int nj = 0; nj < 2; nj++) {
            int n = n0 + nj * 32 + n_lane;
            float wsn = wscale[n];
            float bn = bias[n];
            v16i A = accs[mi][nj];
            #pragma unroll
            for (int r = 0; r < 16; r++) {
                int ml = mi * 32 + (r & 3) + 8 * (r >> 2) + 4 * sel;
                __builtin_nontemporal_store(
                    (float)A[r] * xs[ml] * wsn + bn,
                    &out[(size_t)(m0 + ml) * N + n]);
            }
        }
    }
}

extern "C" void kernel_launch(void* const* d_in, const int* in_sizes, int n_in,
                              void* d_out, int out_size, void* d_ws, size_t ws_size,
                              hipStream_t stream)
{
    const float* x    = (const float*)d_in[0];
    const float* w    = (const float*)d_in[1];
    const float* bias = (const float*)d_in[2];
    float* out = (float*)d_out;

    int DOUT = in_sizes[2];        // 1024
    int M = in_sizes[0] / DIN;     // 32768

    char* ws   = (char*)d_ws;
    char* wq   = ws;                                    // DOUT*DIN int8
    float* wsc = (float*)(wq + (size_t)DOUT * DIN);     // DOUT f32

    quant_w<<<DOUT / 4, 256, 0, stream>>>(w, wq, wsc);
    gemm_i8_fused<<<(M / 64) * 2, 512, 0, stream>>>(x, wq, wsc, bias, out, DOUT);
}